// Round 8
// baseline (213.658 us; speedup 1.0000x reference)
//
#include <hip/hip_runtime.h>
#include <hip/hip_bf16.h>

#define NROWS 131072
#define KEXP 16
#define MPC 128
#define DIMD 64

typedef float f32x4  __attribute__((ext_vector_type(4)));
typedef float f32x16 __attribute__((ext_vector_type(16)));
typedef short s16x8  __attribute__((ext_vector_type(8)));

#define L2E 1.4426950408889634f
#define LN2 0.6931471805599453f

static __device__ inline unsigned int b2u(__hip_bfloat162 h) {
    union { __hip_bfloat162 h; unsigned int u; } c;
    c.h = h;
    return c.u;
}

static __device__ inline int4 cvt8s(float4 f0, float4 f1, float sc) {
    __hip_bfloat162 p0 = __float22bfloat162_rn(make_float2(f0.x * sc, f0.y * sc));
    __hip_bfloat162 p1 = __float22bfloat162_rn(make_float2(f0.z * sc, f0.w * sc));
    __hip_bfloat162 p2 = __float22bfloat162_rn(make_float2(f1.x * sc, f1.y * sc));
    __hip_bfloat162 p3 = __float22bfloat162_rn(make_float2(f1.z * sc, f1.w * sc));
    int4 pk;
    pk.x = (int)b2u(p0); pk.y = (int)b2u(p1); pk.z = (int)b2u(p2); pk.w = (int)b2u(p3);
    return pk;
}

// abff: per expert 20 chunks [mt(4)][c(5)] of 64 int4 (1 KB each) = 20 KB.
//   c<4 : A-frag, value j = a[k][mt*32 + (ul&31)][c*16 + (ul>>5)*8 + j] * L2E
//   c==4: bias chunk — A[m][k'=0] = b[k][mt*32+m] * L2E (ul<32, element 0), else 0
__global__ void prep_kernel(const float* __restrict__ a, const float* __restrict__ b,
                            short* __restrict__ abff) {
    const int u   = blockIdx.x * 256 + threadIdx.x;   // 0..20479
    const int k   = u / 1280;
    const int rem = u - k * 1280;
    const int mt  = rem / 320;
    const int rc  = rem - mt * 320;
    const int c   = rc >> 6;
    const int ul  = rc & 63;
    int4 pk;
    if (c < 4) {
        const float* p = a + (size_t)(k * MPC + mt * 32 + (ul & 31)) * DIMD
                           + c * 16 + (ul >> 5) * 8;
        pk = cvt8s(*(const float4*)(p), *(const float4*)(p + 4), L2E);
    } else {
        pk.x = 0; pk.y = 0; pk.z = 0; pk.w = 0;
        if (ul < 32) {
            union { __hip_bfloat16 h; unsigned short us; } cv;
            cv.h = __float2bfloat16(b[k * MPC + mt * 32 + ul] * L2E);
            pk.x = (int)cv.us;   // element 0 = bias, elements 1..7 = 0
        }
    }
    *(int4*)(abff + (size_t)u * 8) = pk;
}

// NO LDS, NO BARRIERS. Block = 256 threads (4 free-running waves); wave owns
// 64 rows (2 n-tiles) of x persistent in registers (Bf[2][4], 32 VGPR).
// family = blockIdx&1 -> experts family*8..+7; grid = 1024 (4 blocks/CU,
// 16 waves/CU, VGPR budget 128 via __launch_bounds__(256,4) — ~104 used).
// Per expert per mt: 5 coalesced global dwordx4 (Af, L2-hot 320 KB abff),
// two INTERLEAVED independent 5-MFMA chains (n-tile A/B, ILP=2), then in-lane
// exp2 sums. Bias rides as 5th MFMA chunk (constant B = 1.0 at k'=0).
// One shfl_xor(32) per (expert, ntile); families combine via atomicAdd.
__global__ __launch_bounds__(256, 4)
void fused_kernel(const float* __restrict__ x, const float* __restrict__ s,
                  const short* __restrict__ abff, float* __restrict__ out) {
    const int tid  = threadIdx.x;
    const int w    = tid >> 6;
    const int l    = tid & 63;
    const int ln   = l & 31;
    const int half = l >> 5;

    const int family = blockIdx.x & 1;
    const int r0w    = (blockIdx.x >> 1) * 256 + w * 64;

    // persistent x B-fragments: Bf[nt][c] = x[r0w + nt*32 + ln][c*16 + half*8 ..+7]
    union { int4 i; s16x8 v; } Bf[2][4];
#pragma unroll
    for (int nt = 0; nt < 2; ++nt)
#pragma unroll
        for (int c = 0; c < 4; ++c) {
            const float* gp = x + (size_t)(r0w + nt * 32 + ln) * DIMD + c * 16 + half * 8;
            float4 f0 = *(const float4*)(gp);
            float4 f1 = *(const float4*)(gp + 4);
            Bf[nt][c].i = cvt8s(f0, f1, 1.0f);
        }

    // constant bias-B: B[n][k'=0] = 1.0 (k'=0 lives on half==0 lanes, element 0)
    union { int4 i; s16x8 v; } Bones;
    Bones.i.x = (half == 0) ? 0x3F80 : 0;   // bf16(1.0) in element 0
    Bones.i.y = 0; Bones.i.z = 0; Bones.i.w = 0;

    float racc0 = 0.f, racc1 = 0.f;

    for (int k = 0; k < 8; ++k) {
        const int   kf   = family * 8 + k;
        const float sk2  = s[kf] * LN2;
        const short* base = abff + (size_t)kf * 10240 + l * 8;

        float esum0 = 0.f, esum1 = 0.f;

#pragma unroll
        for (int mt = 0; mt < 4; ++mt) {
            // A-frags incl. bias chunk, straight from L2-resident global
            s16x8 Af[5];
#pragma unroll
            for (int c = 0; c < 5; ++c)
                Af[c] = *(const s16x8*)(base + (mt * 5 + c) * 512);

            // two independent chains, interleaved issue (ILP = 2)
            f32x16 accA = {}, accB = {};
#pragma unroll
            for (int c = 0; c < 4; ++c) {
                accA = __builtin_amdgcn_mfma_f32_32x32x16_bf16(Af[c], Bf[0][c].v, accA, 0, 0, 0);
                accB = __builtin_amdgcn_mfma_f32_32x32x16_bf16(Af[c], Bf[1][c].v, accB, 0, 0, 0);
            }
            accA = __builtin_amdgcn_mfma_f32_32x32x16_bf16(Af[4], Bones.v, accA, 0, 0, 0);
            accB = __builtin_amdgcn_mfma_f32_32x32x16_bf16(Af[4], Bones.v, accB, 0, 0, 0);

            // in-lane exp2 sums over this mtile's 16 m-rows (4 parallel temps each)
            {
                float a0 = 0.f, a1 = 0.f, a2 = 0.f, a3 = 0.f;
                float b0 = 0.f, b1 = 0.f, b2 = 0.f, b3 = 0.f;
#pragma unroll
                for (int r = 0; r < 4; ++r) {
                    a0 += __builtin_amdgcn_exp2f(accA[4 * r + 0]);
                    a1 += __builtin_amdgcn_exp2f(accA[4 * r + 1]);
                    a2 += __builtin_amdgcn_exp2f(accA[4 * r + 2]);
                    a3 += __builtin_amdgcn_exp2f(accA[4 * r + 3]);
                    b0 += __builtin_amdgcn_exp2f(accB[4 * r + 0]);
                    b1 += __builtin_amdgcn_exp2f(accB[4 * r + 1]);
                    b2 += __builtin_amdgcn_exp2f(accB[4 * r + 2]);
                    b3 += __builtin_amdgcn_exp2f(accB[4 * r + 3]);
                }
                esum0 += (a0 + a1) + (a2 + a3);
                esum1 += (b0 + b1) + (b2 + b3);
            }
        }

        // combine m-halves (lanes l and l^32), accumulate weighted lse
        float tot0 = esum0 + __shfl_xor(esum0, 32);
        float tot1 = esum1 + __shfl_xor(esum1, 32);
        racc0 = fmaf(sk2, __log2f(tot0), racc0);
        racc1 = fmaf(sk2, __log2f(tot1), racc1);
    }

    // half 0 lanes own n-tile 0 rows, half 1 lanes own n-tile 1 rows
    atomicAdd(&out[r0w + half * 32 + ln], half ? racc1 : racc0);
}

extern "C" void kernel_launch(void* const* d_in, const int* in_sizes, int n_in,
                              void* d_out, int out_size, void* d_ws, size_t ws_size,
                              hipStream_t stream) {
    const float* x = (const float*)d_in[0];
    const float* s = (const float*)d_in[1];
    const float* a = (const float*)d_in[2];
    const float* b = (const float*)d_in[3];
    float* out = (float*)d_out;

    short* abff = (short*)d_ws;   // 16 experts x 20 KB = 320 KB, frag-ordered

    hipMemsetAsync(d_out, 0, (size_t)NROWS * sizeof(float), stream);
    prep_kernel<<<80, 256, 0, stream>>>(a, b, abff);
    fused_kernel<<<NROWS / 128, 256, 0, stream>>>(x, s, abff, out);
}

// Round 9
// 127.604 us; speedup vs baseline: 1.6744x; 1.6744x over previous
//
#include <hip/hip_runtime.h>
#include <hip/hip_bf16.h>

#define NROWS 131072
#define KEXP 16
#define MPC 128
#define DIMD 64

typedef float f32x4  __attribute__((ext_vector_type(4)));
typedef float f32x16 __attribute__((ext_vector_type(16)));
typedef short s16x8  __attribute__((ext_vector_type(8)));

#define L2E 1.4426950408889634f
#define LN2 0.6931471805599453f

static __device__ inline unsigned int b2u(__hip_bfloat162 h) {
    union { __hip_bfloat162 h; unsigned int u; } c;
    c.h = h;
    return c.u;
}

static __device__ inline int4 cvt8s(float4 f0, float4 f1, float sc) {
    __hip_bfloat162 p0 = __float22bfloat162_rn(make_float2(f0.x * sc, f0.y * sc));
    __hip_bfloat162 p1 = __float22bfloat162_rn(make_float2(f0.z * sc, f0.w * sc));
    __hip_bfloat162 p2 = __float22bfloat162_rn(make_float2(f1.x * sc, f1.y * sc));
    __hip_bfloat162 p3 = __float22bfloat162_rn(make_float2(f1.z * sc, f1.w * sc));
    int4 pk;
    pk.x = (int)b2u(p0); pk.y = (int)b2u(p1); pk.z = (int)b2u(p2); pk.w = (int)b2u(p3);
    return pk;
}

// abff: per expert 20 chunks [mt(4)][c(5)] of 64 int4 (1 KB each) = 20 KB.
//   c<4 : A-frag, value j = a[k][mt*32 + (ul&31)][c*16 + (ul>>5)*8 + j] * L2E
//   c==4: bias chunk — A[m][k'=0] = b[k][mt*32+m] * L2E (ul<32, element 0), else 0
__global__ void prep_kernel(const float* __restrict__ a, const float* __restrict__ b,
                            short* __restrict__ abff) {
    const int u   = blockIdx.x * 256 + threadIdx.x;   // 0..20479
    const int k   = u / 1280;
    const int rem = u - k * 1280;
    const int mt  = rem / 320;
    const int rc  = rem - mt * 320;
    const int c   = rc >> 6;
    const int ul  = rc & 63;
    int4 pk;
    if (c < 4) {
        const float* p = a + (size_t)(k * MPC + mt * 32 + (ul & 31)) * DIMD
                           + c * 16 + (ul >> 5) * 8;
        pk = cvt8s(*(const float4*)(p), *(const float4*)(p + 4), L2E);
    } else {
        pk.x = 0; pk.y = 0; pk.z = 0; pk.w = 0;
        if (ul < 32) {
            union { __hip_bfloat16 h; unsigned short us; } cv;
            cv.h = __float2bfloat16(b[k * MPC + mt * 32 + ul] * L2E);
            pk.x = (int)cv.us;   // element 0 = bias, elements 1..7 = 0
        }
    }
    *(int4*)(abff + (size_t)u * 8) = pk;
}

// NO LDS, NO BARRIERS. Block = 256 threads (4 free-running waves); wave owns
// 64 rows (2 n-tiles) of x persistent in registers (Bf[2][4], 32 VGPR).
// family = blockIdx&1 -> experts family*8..+7.
// __launch_bounds__(256,3): reg cap ~170 — fits the ~150-reg live set with NO
// spill (round 8's (256,4)=128-cap spilled 326 MB) and keeps acc in arch VGPRs
// (no v_accvgpr move tax). 3 waves/EU = 12 free-running waves/CU.
// Per expert per mt: 5 coalesced global dwordx4 (Af, L2-hot 320 KB abff),
// two INTERLEAVED independent 5-MFMA chains (n-tile A/B, ILP=2), then in-lane
// exp2 sums. Bias rides as 5th MFMA chunk (constant B = 1.0 at k'=0).
// One shfl_xor(32) per (expert, ntile); families combine via atomicAdd.
__global__ __launch_bounds__(256, 3)
void fused_kernel(const float* __restrict__ x, const float* __restrict__ s,
                  const short* __restrict__ abff, float* __restrict__ out) {
    const int tid  = threadIdx.x;
    const int w    = tid >> 6;
    const int l    = tid & 63;
    const int ln   = l & 31;
    const int half = l >> 5;

    const int family = blockIdx.x & 1;
    const int r0w    = (blockIdx.x >> 1) * 256 + w * 64;

    // persistent x B-fragments: Bf[nt][c] = x[r0w + nt*32 + ln][c*16 + half*8 ..+7]
    union { int4 i; s16x8 v; } Bf[2][4];
#pragma unroll
    for (int nt = 0; nt < 2; ++nt)
#pragma unroll
        for (int c = 0; c < 4; ++c) {
            const float* gp = x + (size_t)(r0w + nt * 32 + ln) * DIMD + c * 16 + half * 8;
            float4 f0 = *(const float4*)(gp);
            float4 f1 = *(const float4*)(gp + 4);
            Bf[nt][c].i = cvt8s(f0, f1, 1.0f);
        }

    // constant bias-B: B[n][k'=0] = 1.0 (k'=0 lives on half==0 lanes, element 0)
    union { int4 i; s16x8 v; } Bones;
    Bones.i.x = (half == 0) ? 0x3F80 : 0;   // bf16(1.0) in element 0
    Bones.i.y = 0; Bones.i.z = 0; Bones.i.w = 0;

    float racc0 = 0.f, racc1 = 0.f;

    for (int k = 0; k < 8; ++k) {
        const int   kf   = family * 8 + k;
        const float sk2  = s[kf] * LN2;
        const short* base = abff + (size_t)kf * 10240 + l * 8;

        float esum0 = 0.f, esum1 = 0.f;

#pragma unroll
        for (int mt = 0; mt < 4; ++mt) {
            // A-frags incl. bias chunk, straight from L2-resident global
            s16x8 Af[5];
#pragma unroll
            for (int c = 0; c < 5; ++c)
                Af[c] = *(const s16x8*)(base + (mt * 5 + c) * 512);

            // two independent chains, interleaved issue (ILP = 2)
            f32x16 accA = {}, accB = {};
#pragma unroll
            for (int c = 0; c < 4; ++c) {
                accA = __builtin_amdgcn_mfma_f32_32x32x16_bf16(Af[c], Bf[0][c].v, accA, 0, 0, 0);
                accB = __builtin_amdgcn_mfma_f32_32x32x16_bf16(Af[c], Bf[1][c].v, accB, 0, 0, 0);
            }
            accA = __builtin_amdgcn_mfma_f32_32x32x16_bf16(Af[4], Bones.v, accA, 0, 0, 0);
            accB = __builtin_amdgcn_mfma_f32_32x32x16_bf16(Af[4], Bones.v, accB, 0, 0, 0);

            // in-lane exp2 sums over this mtile's 16 m-rows (4 parallel temps each)
            {
                float a0 = 0.f, a1 = 0.f, a2 = 0.f, a3 = 0.f;
                float b0 = 0.f, b1 = 0.f, b2 = 0.f, b3 = 0.f;
#pragma unroll
                for (int r = 0; r < 4; ++r) {
                    a0 += __builtin_amdgcn_exp2f(accA[4 * r + 0]);
                    a1 += __builtin_amdgcn_exp2f(accA[4 * r + 1]);
                    a2 += __builtin_amdgcn_exp2f(accA[4 * r + 2]);
                    a3 += __builtin_amdgcn_exp2f(accA[4 * r + 3]);
                    b0 += __builtin_amdgcn_exp2f(accB[4 * r + 0]);
                    b1 += __builtin_amdgcn_exp2f(accB[4 * r + 1]);
                    b2 += __builtin_amdgcn_exp2f(accB[4 * r + 2]);
                    b3 += __builtin_amdgcn_exp2f(accB[4 * r + 3]);
                }
                esum0 += (a0 + a1) + (a2 + a3);
                esum1 += (b0 + b1) + (b2 + b3);
            }
        }

        // combine m-halves (lanes l and l^32), accumulate weighted lse
        float tot0 = esum0 + __shfl_xor(esum0, 32);
        float tot1 = esum1 + __shfl_xor(esum1, 32);
        racc0 = fmaf(sk2, __log2f(tot0), racc0);
        racc1 = fmaf(sk2, __log2f(tot1), racc1);
    }

    // half 0 lanes own n-tile 0 rows, half 1 lanes own n-tile 1 rows
    atomicAdd(&out[r0w + half * 32 + ln], half ? racc1 : racc0);
}

extern "C" void kernel_launch(void* const* d_in, const int* in_sizes, int n_in,
                              void* d_out, int out_size, void* d_ws, size_t ws_size,
                              hipStream_t stream) {
    const float* x = (const float*)d_in[0];
    const float* s = (const float*)d_in[1];
    const float* a = (const float*)d_in[2];
    const float* b = (const float*)d_in[3];
    float* out = (float*)d_out;

    short* abff = (short*)d_ws;   // 16 experts x 20 KB = 320 KB, frag-ordered

    hipMemsetAsync(d_out, 0, (size_t)NROWS * sizeof(float), stream);
    prep_kernel<<<80, 256, 0, stream>>>(a, b, abff);
    fused_kernel<<<NROWS / 128, 256, 0, stream>>>(x, s, abff, out);
}